// Round 4
// baseline (266.841 us; speedup 1.0000x reference)
//
#include <hip/hip_runtime.h>
#include <hip/hip_bf16.h>
#include <math.h>

#define B_ 4
#define S_ 4096
#define E_ 1024

typedef __attribute__((ext_vector_type(8))) short bf16x8;
typedef __attribute__((ext_vector_type(4))) short bf16x4;
typedef __attribute__((ext_vector_type(4))) float f32x4;

__device__ __forceinline__ unsigned short f2bf(float f) {
  unsigned u = __float_as_uint(f);
  u = u + 0x7fffu + ((u >> 16) & 1u);
  return (unsigned short)(u >> 16);
}

// ---------------- projection: Q/K/Vt = x @ W^T ----------------
// (verbatim round-1 — proven correct)
__global__ __launch_bounds__(256) void proj_kernel(
    const float* __restrict__ x, const float* __restrict__ Wq,
    const float* __restrict__ Wk, const float* __restrict__ Wv,
    unsigned short* __restrict__ Qp, unsigned short* __restrict__ Kb,
    unsigned short* __restrict__ Vt)
{
  __shared__ __align__(16) unsigned short xs[64*64];   // [64 m][64 k] bf16, XOR-swizzled
  __shared__ __align__(16) unsigned short wl[192*64];  // [192 n][64 k] bf16, XOR-swizzled
  const int tid = threadIdx.x;
  const int wave = tid >> 6, lane = tid & 63;
  const int l15 = lane & 15, l4 = lane >> 4;
  const int m0 = blockIdx.x * 64;

  f32x4 acc[12];
  #pragma unroll
  for (int i = 0; i < 12; i++) acc[i] = (f32x4)0.f;

  f32x4 xr[4], wr[12];
  #pragma unroll
  for (int i = 0; i < 4; i++) {
    int c = tid + i*256; int row = c >> 4, cc = c & 15;
    xr[i] = *(const f32x4*)(x + (size_t)(m0 + row)*E_ + cc*4);
  }
  #pragma unroll
  for (int i = 0; i < 12; i++) {
    int c = tid + i*256; int n = c >> 4, cc = c & 15;
    const float* Wsrc = (n < 64) ? (Wq + (size_t)n*E_)
                     : ((n < 128) ? (Wk + (size_t)(n-64)*E_)
                                  : (Wv + (size_t)(n-128)*E_));
    wr[i] = *(const f32x4*)(Wsrc + cc*4);
  }

  for (int ks = 0; ks < 16; ks++) {
    __syncthreads();
    #pragma unroll
    for (int i = 0; i < 4; i++) {
      int c = tid + i*256; int row = c >> 4, cc = c & 15;
      bf16x4 v;
      v[0] = (short)f2bf(xr[i][0]); v[1] = (short)f2bf(xr[i][1]);
      v[2] = (short)f2bf(xr[i][2]); v[3] = (short)f2bf(xr[i][3]);
      *(bf16x4*)((char*)xs + row*128 + ((cc*8) ^ ((row&7)<<4))) = v;
    }
    #pragma unroll
    for (int i = 0; i < 12; i++) {
      int c = tid + i*256; int n = c >> 4, cc = c & 15;
      bf16x4 v;
      v[0] = (short)f2bf(wr[i][0]); v[1] = (short)f2bf(wr[i][1]);
      v[2] = (short)f2bf(wr[i][2]); v[3] = (short)f2bf(wr[i][3]);
      *(bf16x4*)((char*)wl + n*128 + ((cc*8) ^ ((n&7)<<4))) = v;
    }
    if (ks < 15) {
      #pragma unroll
      for (int i = 0; i < 4; i++) {
        int c = tid + i*256; int row = c >> 4, cc = c & 15;
        xr[i] = *(const f32x4*)(x + (size_t)(m0 + row)*E_ + (ks+1)*64 + cc*4);
      }
      #pragma unroll
      for (int i = 0; i < 12; i++) {
        int c = tid + i*256; int n = c >> 4, cc = c & 15;
        const float* Wsrc = (n < 64) ? (Wq + (size_t)n*E_)
                         : ((n < 128) ? (Wk + (size_t)(n-64)*E_)
                                      : (Wv + (size_t)(n-128)*E_));
        wr[i] = *(const f32x4*)(Wsrc + (ks+1)*64 + cc*4);
      }
    }
    __syncthreads();
    const int arow = wave*16 + l15;
    const int aswz = (arow&7)<<4;
    bf16x8 a0 = *(const bf16x8*)((const char*)xs + arow*128 + ((l4*16) ^ aswz));
    bf16x8 a1 = *(const bf16x8*)((const char*)xs + arow*128 + ((64 + l4*16) ^ aswz));
    #pragma unroll
    for (int ntl = 0; ntl < 12; ntl++) {
      int brow = ntl*16 + l15;
      int bswz = (brow&7)<<4;
      bf16x8 b0 = *(const bf16x8*)((const char*)wl + brow*128 + ((l4*16) ^ bswz));
      bf16x8 b1 = *(const bf16x8*)((const char*)wl + brow*128 + ((64 + l4*16) ^ bswz));
      acc[ntl] = __builtin_amdgcn_mfma_f32_16x16x32_bf16(a0, b0, acc[ntl], 0, 0, 0);
      acc[ntl] = __builtin_amdgcn_mfma_f32_16x16x32_bf16(a1, b1, acc[ntl], 0, 0, 0);
    }
  }

  const float QSC = 0.04508422f;  // log2(e) / sqrt(1024)
  const int mb = m0 + wave*16 + l4*4;
  #pragma unroll
  for (int ntl = 0; ntl < 4; ntl++) {
    int col = ntl*16 + l15;
    #pragma unroll
    for (int r = 0; r < 4; r++)
      Qp[(size_t)(mb + r)*64 + col] = f2bf(acc[ntl][r] * QSC);
  }
  #pragma unroll
  for (int ntl = 0; ntl < 4; ntl++) {
    int col = ntl*16 + l15;
    #pragma unroll
    for (int r = 0; r < 4; r++)
      Kb[(size_t)(mb + r)*64 + col] = f2bf(acc[4+ntl][r]);
  }
  const int b = m0 >> 12;
  const int sb = (m0 & 4095) + wave*16 + l4*4;
  #pragma unroll
  for (int ntl = 0; ntl < 4; ntl++) {
    int d = ntl*16 + l15;
    bf16x4 v;
    #pragma unroll
    for (int r = 0; r < 4; r++) v[r] = (short)f2bf(acc[8+ntl][r]);
    *(bf16x4*)(Vt + (size_t)(b*64 + d)*S_ + sb) = v;
  }
}

// ---------------- causal flash attention ----------------
// Round-1 math verbatim, but NO K/V LDS staging: each wave loads its MFMA
// fragments directly global->register (K/V are L2-resident: 1MB/batch,
// batch pinned to 2 XCDs by bid swizzle). Zero barriers in the tile loop;
// explicit next-tile register double-buffer. Merge via LDS at the end.
__global__ __launch_bounds__(256) void attn_kernel(
    const unsigned short* __restrict__ Qp,
    const unsigned short* __restrict__ Kb,
    const unsigned short* __restrict__ Vt,
    float* __restrict__ out)
{
  __shared__ __align__(16) float mergeO[4][16][68];  // padded: conflict-free
  __shared__ float mstats[4][16][2];

  const int tid = threadIdx.x;
  const int wave = tid >> 6, lane = tid & 63;
  const int l15 = lane & 15, l4 = lane >> 4;
  const int g = wave >> 1, h = wave & 1;

  const int bid = blockIdx.x;            // 0..511
  const int u = bid >> 1, par = bid & 1;
  const int b = u & 3;
  const int pp = u >> 2;                 // 0..63
  const int jq = par ? (127 - pp) : pp;  // light/heavy interleaved

  const unsigned short* Qb  = Qp + (size_t)b*S_*64;
  const unsigned short* Kbb = Kb + (size_t)b*S_*64;
  const unsigned short* Vtb = Vt + (size_t)b*64*S_;
  float* outb = out + (size_t)b*S_*64;

  const int q0 = jq * 32;
  const int ntile = (jq >> 1) + 1;
  const int qrow = q0 + g*16 + l15;

  bf16x8 qf0 = *(const bf16x8*)(Qb + (size_t)qrow*64 + l4*8);
  bf16x8 qf1 = *(const bf16x8*)(Qb + (size_t)qrow*64 + 32 + l4*8);

  float m = -INFINITY, lsum = 0.f;
  f32x4 acc[4];
  #pragma unroll
  for (int i = 0; i < 4; i++) acc[i] = (f32x4)0.f;

  // fragment register sets (all indices static after unroll)
  bf16x8 kfA[4], kfB[4];   // [st*2 + (0: d0..31, 1: d32..63)]
  bf16x4 vfA[8], vfB[8];   // [dt*2 + (0: k+0..3, 1: k+16..19)]

  // K frag row: (t*64 + (2h+st)*16 + l15), d = l4*8 (+32)  [== LDS read of r1]
  // V frag row: (dt*16 + l15), k = t*64 + h*32 + l4*4 (+16) [== LDS read of r1]
  #define LOADF(KF, VF, tt) do {                                               \
    _Pragma("unroll")                                                          \
    for (int st = 0; st < 2; st++) {                                           \
      const unsigned short* kp =                                               \
          Kbb + (size_t)((tt)*64 + (2*h + st)*16 + l15)*64 + l4*8;             \
      KF[st*2+0] = *(const bf16x8*)kp;                                         \
      KF[st*2+1] = *(const bf16x8*)(kp + 32);                                  \
    }                                                                          \
    _Pragma("unroll")                                                          \
    for (int dt = 0; dt < 4; dt++) {                                           \
      const unsigned short* vp =                                               \
          Vtb + (size_t)(dt*16 + l15)*S_ + (tt)*64 + h*32 + l4*4;              \
      VF[dt*2+0] = *(const bf16x4*)vp;                                         \
      VF[dt*2+1] = *(const bf16x4*)(vp + 16);                                  \
    }                                                                          \
  } while (0)

  #define COMPUTE(KF, VF, tt) do {                                             \
    f32x4 sv0 = (f32x4)0.f, sv1 = (f32x4)0.f;                                  \
    sv0 = __builtin_amdgcn_mfma_f32_16x16x32_bf16(KF[0], qf0, sv0, 0, 0, 0);   \
    sv0 = __builtin_amdgcn_mfma_f32_16x16x32_bf16(KF[1], qf1, sv0, 0, 0, 0);   \
    sv1 = __builtin_amdgcn_mfma_f32_16x16x32_bf16(KF[2], qf0, sv1, 0, 0, 0);   \
    sv1 = __builtin_amdgcn_mfma_f32_16x16x32_bf16(KF[3], qf1, sv1, 0, 0, 0);   \
    if ((tt) == ntile - 1) {                                                   \
      _Pragma("unroll")                                                        \
      for (int r = 0; r < 4; r++) {                                            \
        int kg0 = (tt)*64 + (2*h + 0)*16 + l4*4 + r;                           \
        int kg1 = (tt)*64 + (2*h + 1)*16 + l4*4 + r;                           \
        if (kg0 > qrow) sv0[r] = -INFINITY;                                    \
        if (kg1 > qrow) sv1[r] = -INFINITY;                                    \
      }                                                                        \
    }                                                                          \
    float pmax = sv0[0];                                                       \
    _Pragma("unroll")                                                          \
    for (int r = 0; r < 4; r++) {                                              \
      pmax = fmaxf(pmax, sv0[r]); pmax = fmaxf(pmax, sv1[r]);                  \
    }                                                                          \
    pmax = fmaxf(pmax, __shfl_xor(pmax, 16, 64));                              \
    pmax = fmaxf(pmax, __shfl_xor(pmax, 32, 64));                              \
    float mnew = fmaxf(m, pmax);                                               \
    float msafe = (mnew == -INFINITY) ? 0.f : mnew;                            \
    float scale = exp2f(m - msafe);                                            \
    float pv[8]; float psum = 0.f;                                             \
    _Pragma("unroll")                                                          \
    for (int i = 0; i < 8; i++) {                                              \
      float s = (i < 4) ? sv0[i & 3] : sv1[i & 3];                             \
      pv[i] = exp2f(s - msafe);                                                \
      psum += pv[i];                                                           \
    }                                                                          \
    psum += __shfl_xor(psum, 16, 64);                                          \
    psum += __shfl_xor(psum, 32, 64);                                          \
    lsum = lsum*scale + psum;                                                  \
    m = mnew;                                                                  \
    _Pragma("unroll")                                                          \
    for (int i = 0; i < 4; i++) acc[i] *= scale;                               \
    bf16x8 pf;                                                                 \
    _Pragma("unroll")                                                          \
    for (int i = 0; i < 8; i++) pf[i] = (short)f2bf(pv[i]);                    \
    _Pragma("unroll")                                                          \
    for (int dt = 0; dt < 4; dt++) {                                           \
      bf16x8 vf;                                                               \
      _Pragma("unroll")                                                        \
      for (int i = 0; i < 4; i++) {                                            \
        vf[i] = VF[dt*2+0][i]; vf[i+4] = VF[dt*2+1][i];                        \
      }                                                                        \
      acc[dt] = __builtin_amdgcn_mfma_f32_16x16x32_bf16(vf, pf, acc[dt], 0, 0, 0); \
    }                                                                          \
  } while (0)

  LOADF(kfA, vfA, 0);
  for (int t = 0; t < ntile; t += 2) {
    if (t + 1 < ntile) LOADF(kfB, vfB, t + 1);
    COMPUTE(kfA, vfA, t);
    if (t + 1 < ntile) {
      if (t + 2 < ntile) LOADF(kfA, vfA, t + 2);
      COMPUTE(kfB, vfB, t + 1);
    }
  }
  #undef LOADF
  #undef COMPUTE

  // merge the two k-half partials, normalize, store (verbatim round-1)
  __syncthreads();
  #pragma unroll
  for (int dt = 0; dt < 4; dt++)
    *(f32x4*)&mergeO[wave][l15][dt*16 + l4*4] = acc[dt];
  if (lane < 16) { mstats[wave][lane][0] = m; mstats[wave][lane][1] = lsum; }
  __syncthreads();
  {
    int ql = tid >> 3, dc = tid & 7;
    int gg = ql >> 4, q16 = ql & 15;
    float m1 = mstats[gg*2+0][q16][0], s1 = mstats[gg*2+0][q16][1];
    float m2 = mstats[gg*2+1][q16][0], s2 = mstats[gg*2+1][q16][1];
    float m12 = fmaxf(m1, m2);
    float a1 = exp2f(m1 - m12), a2 = exp2f(m2 - m12);
    float inv = 1.f / (s1*a1 + s2*a2);
    a1 *= inv; a2 *= inv;
    #pragma unroll
    for (int i = 0; i < 2; i++) {
      int d = dc*8 + i*4;
      f32x4 o1 = *(const f32x4*)&mergeO[gg*2+0][q16][d];
      f32x4 o2 = *(const f32x4*)&mergeO[gg*2+1][q16][d];
      f32x4 o = o1*a1 + o2*a2;
      *(f32x4*)(outb + (size_t)(q0 + ql)*64 + d) = o;
    }
  }
}

extern "C" void kernel_launch(void* const* d_in, const int* in_sizes, int n_in,
                              void* d_out, int out_size, void* d_ws, size_t ws_size,
                              hipStream_t stream)
{
  const float* x  = (const float*)d_in[0];
  const float* Wq = (const float*)d_in[1];
  const float* Wk = (const float*)d_in[2];
  const float* Wv = (const float*)d_in[3];
  unsigned short* Qp  = (unsigned short*)d_ws;                 // 2 MB
  unsigned short* Kbp = Qp  + (size_t)B_*S_*64;                // 2 MB
  unsigned short* Vtp = Kbp + (size_t)B_*S_*64;                // 2 MB
  float* out = (float*)d_out;

  hipLaunchKernelGGL(proj_kernel, dim3(256), dim3(256), 0, stream,
                     x, Wq, Wk, Wv, Qp, Kbp, Vtp);
  hipLaunchKernelGGL(attn_kernel, dim3(512), dim3(256), 0, stream,
                     Qp, Kbp, Vtp, out);
}

// Round 5
// 160.702 us; speedup vs baseline: 1.6605x; 1.6605x over previous
//
#include <hip/hip_runtime.h>
#include <hip/hip_bf16.h>
#include <math.h>

#define B_ 4
#define S_ 4096
#define E_ 1024

typedef __attribute__((ext_vector_type(8))) short bf16x8;
typedef __attribute__((ext_vector_type(4))) short bf16x4;
typedef __attribute__((ext_vector_type(4))) float f32x4;

__device__ __forceinline__ unsigned short f2bf(float f) {
  unsigned u = __float_as_uint(f);
  u = u + 0x7fffu + ((u >> 16) & 1u);
  return (unsigned short)(u >> 16);
}

// ---------------- projection: Q/K/Vt = x @ W^T ----------------
// (verbatim round-1 — proven correct)
__global__ __launch_bounds__(256) void proj_kernel(
    const float* __restrict__ x, const float* __restrict__ Wq,
    const float* __restrict__ Wk, const float* __restrict__ Wv,
    unsigned short* __restrict__ Qp, unsigned short* __restrict__ Kb,
    unsigned short* __restrict__ Vt)
{
  __shared__ __align__(16) unsigned short xs[64*64];   // [64 m][64 k] bf16, XOR-swizzled
  __shared__ __align__(16) unsigned short wl[192*64];  // [192 n][64 k] bf16, XOR-swizzled
  const int tid = threadIdx.x;
  const int wave = tid >> 6, lane = tid & 63;
  const int l15 = lane & 15, l4 = lane >> 4;
  const int m0 = blockIdx.x * 64;

  f32x4 acc[12];
  #pragma unroll
  for (int i = 0; i < 12; i++) acc[i] = (f32x4)0.f;

  f32x4 xr[4], wr[12];
  #pragma unroll
  for (int i = 0; i < 4; i++) {
    int c = tid + i*256; int row = c >> 4, cc = c & 15;
    xr[i] = *(const f32x4*)(x + (size_t)(m0 + row)*E_ + cc*4);
  }
  #pragma unroll
  for (int i = 0; i < 12; i++) {
    int c = tid + i*256; int n = c >> 4, cc = c & 15;
    const float* Wsrc = (n < 64) ? (Wq + (size_t)n*E_)
                     : ((n < 128) ? (Wk + (size_t)(n-64)*E_)
                                  : (Wv + (size_t)(n-128)*E_));
    wr[i] = *(const f32x4*)(Wsrc + cc*4);
  }

  for (int ks = 0; ks < 16; ks++) {
    __syncthreads();
    #pragma unroll
    for (int i = 0; i < 4; i++) {
      int c = tid + i*256; int row = c >> 4, cc = c & 15;
      bf16x4 v;
      v[0] = (short)f2bf(xr[i][0]); v[1] = (short)f2bf(xr[i][1]);
      v[2] = (short)f2bf(xr[i][2]); v[3] = (short)f2bf(xr[i][3]);
      *(bf16x4*)((char*)xs + row*128 + ((cc*8) ^ ((row&7)<<4))) = v;
    }
    #pragma unroll
    for (int i = 0; i < 12; i++) {
      int c = tid + i*256; int n = c >> 4, cc = c & 15;
      bf16x4 v;
      v[0] = (short)f2bf(wr[i][0]); v[1] = (short)f2bf(wr[i][1]);
      v[2] = (short)f2bf(wr[i][2]); v[3] = (short)f2bf(wr[i][3]);
      *(bf16x4*)((char*)wl + n*128 + ((cc*8) ^ ((n&7)<<4))) = v;
    }
    if (ks < 15) {
      #pragma unroll
      for (int i = 0; i < 4; i++) {
        int c = tid + i*256; int row = c >> 4, cc = c & 15;
        xr[i] = *(const f32x4*)(x + (size_t)(m0 + row)*E_ + (ks+1)*64 + cc*4);
      }
      #pragma unroll
      for (int i = 0; i < 12; i++) {
        int c = tid + i*256; int n = c >> 4, cc = c & 15;
        const float* Wsrc = (n < 64) ? (Wq + (size_t)n*E_)
                         : ((n < 128) ? (Wk + (size_t)(n-64)*E_)
                                      : (Wv + (size_t)(n-128)*E_));
        wr[i] = *(const f32x4*)(Wsrc + (ks+1)*64 + cc*4);
      }
    }
    __syncthreads();
    const int arow = wave*16 + l15;
    const int aswz = (arow&7)<<4;
    bf16x8 a0 = *(const bf16x8*)((const char*)xs + arow*128 + ((l4*16) ^ aswz));
    bf16x8 a1 = *(const bf16x8*)((const char*)xs + arow*128 + ((64 + l4*16) ^ aswz));
    #pragma unroll
    for (int ntl = 0; ntl < 12; ntl++) {
      int brow = ntl*16 + l15;
      int bswz = (brow&7)<<4;
      bf16x8 b0 = *(const bf16x8*)((const char*)wl + brow*128 + ((l4*16) ^ bswz));
      bf16x8 b1 = *(const bf16x8*)((const char*)wl + brow*128 + ((64 + l4*16) ^ bswz));
      acc[ntl] = __builtin_amdgcn_mfma_f32_16x16x32_bf16(a0, b0, acc[ntl], 0, 0, 0);
      acc[ntl] = __builtin_amdgcn_mfma_f32_16x16x32_bf16(a1, b1, acc[ntl], 0, 0, 0);
    }
  }

  const float QSC = 0.04508422f;  // log2(e) / sqrt(1024)
  const int mb = m0 + wave*16 + l4*4;
  #pragma unroll
  for (int ntl = 0; ntl < 4; ntl++) {
    int col = ntl*16 + l15;
    #pragma unroll
    for (int r = 0; r < 4; r++)
      Qp[(size_t)(mb + r)*64 + col] = f2bf(acc[ntl][r] * QSC);
  }
  #pragma unroll
  for (int ntl = 0; ntl < 4; ntl++) {
    int col = ntl*16 + l15;
    #pragma unroll
    for (int r = 0; r < 4; r++)
      Kb[(size_t)(mb + r)*64 + col] = f2bf(acc[4+ntl][r]);
  }
  const int b = m0 >> 12;
  const int sb = (m0 & 4095) + wave*16 + l4*4;
  #pragma unroll
  for (int ntl = 0; ntl < 4; ntl++) {
    int d = ntl*16 + l15;
    bf16x4 v;
    #pragma unroll
    for (int r = 0; r < 4; r++) v[r] = (short)f2bf(acc[8+ntl][r]);
    *(bf16x4*)(Vt + (size_t)(b*64 + d)*S_ + sb) = v;
  }
}

// ---------------- causal flash attention, split-K ----------------
// Round-3 LDS-staged body verbatim. Block = (b, pair p, ks): processes the
// ks-th tile-slice of BOTH jq=p and jq=127-p -> uniform ~65/NS tiles/block.
// NS=1: writes normalized out directly (== round-1 pair kernel).
// NS>1: writes unnormalized partial O + (m,l) stats; merge_kernel combines.
__global__ __launch_bounds__(256) void attn_kernel(
    const unsigned short* __restrict__ Qp,
    const unsigned short* __restrict__ Kb,
    const unsigned short* __restrict__ Vt,
    float* __restrict__ out,
    float* __restrict__ Opart, float* __restrict__ spart, int NS)
{
  __shared__ __align__(16) unsigned short Ks[64*64];  // [64 k][64 d], swizzled
  __shared__ __align__(16) unsigned short Vs[64*64];  // [64 d][64 k], swizzled
  __shared__ __align__(16) float mergeO[4][16][68];   // padded: conflict-free
  __shared__ float mstats[4][16][2];

  const int tid = threadIdx.x;
  const int wave = tid >> 6, lane = tid & 63;
  const int l15 = lane & 15, l4 = lane >> 4;
  const int g = wave >> 1, h = wave & 1;

  const int bid = blockIdx.x;                 // grid = 256*NS
  const int lg = (NS == 4) ? 2 : ((NS == 2) ? 1 : 0);
  const int b  = (bid >> 1) & 3;              // batch -> XCDs {2b,2b+1}
  const int ks = (bid >> 3) & (NS - 1);
  const int p  = ((bid >> (3 + lg)) << 1) | (bid & 1);   // 0..63

  const unsigned short* Qb  = Qp + (size_t)b*S_*64;
  const unsigned short* Kbb = Kb + (size_t)b*S_*64;
  const unsigned short* Vtb = Vt + (size_t)b*64*S_;
  float* outb = out + (size_t)b*S_*64;

  #pragma unroll 1
  for (int half = 0; half < 2; half++) {
    const int jq = half ? (127 - p) : p;
    const int q0 = jq * 32;
    const int ntile = (jq >> 1) + 1;
    // tile slice [kbeg, kend) for this ks
    const int tb = ntile / NS, tr = ntile % NS;
    const int kbeg = ks*tb + (ks < tr ? ks : tr);
    const int kend = kbeg + tb + (ks < tr ? 1 : 0);
    const int qrow = q0 + g*16 + l15;

    bf16x8 qf0 = *(const bf16x8*)(Qb + (size_t)qrow*64 + l4*8);
    bf16x8 qf1 = *(const bf16x8*)(Qb + (size_t)qrow*64 + 32 + l4*8);

    float m = -INFINITY, lsum = 0.f;
    f32x4 acc[4];
    #pragma unroll
    for (int i = 0; i < 4; i++) acc[i] = (f32x4)0.f;

    f32x4 kreg[2], vreg[2];
    if (kbeg < kend) {
      #pragma unroll
      for (int i = 0; i < 2; i++) {
        int c = tid + i*256; int row = c >> 3, cc = c & 7;
        kreg[i] = *(const f32x4*)((const char*)Kbb + (size_t)(kbeg*64 + row)*128 + cc*16);
        vreg[i] = *(const f32x4*)((const char*)Vtb + (size_t)row*8192 + (size_t)kbeg*128 + cc*16);
      }
    }

    for (int t = kbeg; t < kend; t++) {
      __syncthreads();
      #pragma unroll
      for (int i = 0; i < 2; i++) {
        int c = tid + i*256; int row = c >> 3, cc = c & 7;
        *(f32x4*)((char*)Ks + row*128 + ((cc*16) ^ ((row&7)<<4))) = kreg[i];
        *(f32x4*)((char*)Vs + row*128 + ((cc*16) ^ ((row&7)<<4))) = vreg[i];
      }
      if (t + 1 < kend) {
        int k0 = (t+1)*64;
        #pragma unroll
        for (int i = 0; i < 2; i++) {
          int c = tid + i*256; int row = c >> 3, cc = c & 7;
          kreg[i] = *(const f32x4*)((const char*)Kbb + (size_t)(k0+row)*128 + cc*16);
          vreg[i] = *(const f32x4*)((const char*)Vtb + (size_t)row*8192 + (size_t)k0*2 + cc*16);
        }
      }
      __syncthreads();

      // QK^T (this wave's 32-key half: subtiles 2h, 2h+1)
      f32x4 sv[2];
      #pragma unroll
      for (int st = 0; st < 2; st++) {
        int krow = (2*h + st)*16 + l15;
        const char* kbp = (const char*)Ks + krow*128;
        int swz = (krow&7)<<4;
        bf16x8 k0f = *(const bf16x8*)(kbp + ((l4*16) ^ swz));
        bf16x8 k1f = *(const bf16x8*)(kbp + ((64 + l4*16) ^ swz));
        f32x4 z = (f32x4)0.f;
        z = __builtin_amdgcn_mfma_f32_16x16x32_bf16(k0f, qf0, z, 0, 0, 0);
        z = __builtin_amdgcn_mfma_f32_16x16x32_bf16(k1f, qf1, z, 0, 0, 0);
        sv[st] = z;
      }
      if (t == ntile - 1) {
        #pragma unroll
        for (int st = 0; st < 2; st++) {
          #pragma unroll
          for (int r = 0; r < 4; r++) {
            int kg = t*64 + (2*h + st)*16 + l4*4 + r;
            if (kg > qrow) sv[st][r] = -INFINITY;
          }
        }
      }
      // online softmax (base-2; Q pre-scaled by log2e/sqrt(E))
      float pmax = sv[0][0];
      #pragma unroll
      for (int st = 0; st < 2; st++) {
        #pragma unroll
        for (int r = 0; r < 4; r++) pmax = fmaxf(pmax, sv[st][r]);
      }
      pmax = fmaxf(pmax, __shfl_xor(pmax, 16, 64));
      pmax = fmaxf(pmax, __shfl_xor(pmax, 32, 64));
      float mnew = fmaxf(m, pmax);
      float msafe = (mnew == -INFINITY) ? 0.f : mnew;
      float scale = exp2f(m - msafe);
      float pv[8]; float psum = 0.f;
      #pragma unroll
      for (int i = 0; i < 8; i++) {
        pv[i] = exp2f(sv[i>>2][i&3] - msafe);
        psum += pv[i];
      }
      psum += __shfl_xor(psum, 16, 64);
      psum += __shfl_xor(psum, 32, 64);
      lsum = lsum*scale + psum;
      m = mnew;
      #pragma unroll
      for (int i = 0; i < 4; i++) acc[i] *= scale;
      bf16x8 pf;
      #pragma unroll
      for (int i = 0; i < 8; i++) pf[i] = (short)f2bf(pv[i]);
      #pragma unroll
      for (int dt = 0; dt < 4; dt++) {
        int drow = dt*16 + l15;
        const char* vb = (const char*)Vs + drow*128;
        int swz = (drow&7)<<4;
        bf16x4 v0 = *(const bf16x4*)(vb + ((h*64 + l4*8) ^ swz));
        bf16x4 v1 = *(const bf16x4*)(vb + ((h*64 + 32 + l4*8) ^ swz));
        bf16x8 vf;
        #pragma unroll
        for (int i = 0; i < 4; i++) { vf[i] = v0[i]; vf[i+4] = v1[i]; }
        acc[dt] = __builtin_amdgcn_mfma_f32_16x16x32_bf16(vf, pf, acc[dt], 0, 0, 0);
      }
    } // KV tiles

    // merge the two in-block k-halves
    __syncthreads();
    #pragma unroll
    for (int dt = 0; dt < 4; dt++)
      *(f32x4*)&mergeO[wave][l15][dt*16 + l4*4] = acc[dt];
    if (lane < 16) { mstats[wave][lane][0] = m; mstats[wave][lane][1] = lsum; }
    __syncthreads();
    {
      int ql = tid >> 3, dc = tid & 7;
      int gg = ql >> 4, q16 = ql & 15;
      float m1 = mstats[gg*2+0][q16][0], s1 = mstats[gg*2+0][q16][1];
      float m2 = mstats[gg*2+1][q16][0], s2 = mstats[gg*2+1][q16][1];
      float m12 = fmaxf(m1, m2);
      float msafe12 = (m12 == -INFINITY) ? 0.f : m12;   // empty-slice guard
      float a1 = exp2f(m1 - msafe12), a2 = exp2f(m2 - msafe12);
      float s12 = s1*a1 + s2*a2;
      if (NS == 1) {
        float inv = 1.f / s12;
        float b1 = a1*inv, b2 = a2*inv;
        #pragma unroll
        for (int i = 0; i < 2; i++) {
          int d = dc*8 + i*4;
          f32x4 o1 = *(const f32x4*)&mergeO[gg*2+0][q16][d];
          f32x4 o2 = *(const f32x4*)&mergeO[gg*2+1][q16][d];
          f32x4 o = o1*b1 + o2*b2;
          *(f32x4*)(outb + (size_t)(q0 + ql)*64 + d) = o;
        }
      } else {
        int slot = ((b*128 + jq)*NS + ks);
        #pragma unroll
        for (int i = 0; i < 2; i++) {
          int d = dc*8 + i*4;
          f32x4 o1 = *(const f32x4*)&mergeO[gg*2+0][q16][d];
          f32x4 o2 = *(const f32x4*)&mergeO[gg*2+1][q16][d];
          f32x4 o = o1*a1 + o2*a2;       // unnormalized, scale 2^-m12
          *(f32x4*)(Opart + (size_t)slot*2048 + ql*64 + d) = o;
        }
        if (dc == 0) {
          spart[(size_t)slot*64 + ql*2]     = m12;
          spart[(size_t)slot*64 + ql*2 + 1] = s12;
        }
      }
    }
  } // half
}

// ---------------- cross-split merge ----------------
__global__ __launch_bounds__(256) void merge_kernel(
    const float* __restrict__ Opart, const float* __restrict__ spart,
    float* __restrict__ out, int NS)
{
  const int bid = blockIdx.x;          // 512 = 4 batches x 128 jq
  const int b = bid >> 7, jq = bid & 127;
  const int q0 = jq * 32;
  const int ql = threadIdx.x >> 3, dc = threadIdx.x & 7;
  const int base = (b*128 + jq) * NS;

  float M = -INFINITY;
  for (int i = 0; i < NS; i++)
    M = fmaxf(M, spart[(size_t)(base+i)*64 + ql*2]);
  float wsum = 0.f;
  f32x4 o0 = (f32x4)0.f, o1 = (f32x4)0.f;
  for (int i = 0; i < NS; i++) {
    float mi = spart[(size_t)(base+i)*64 + ql*2];
    float li = spart[(size_t)(base+i)*64 + ql*2 + 1];
    float a = exp2f(mi - M);
    wsum += li * a;
    const float* op = Opart + (size_t)(base+i)*2048 + ql*64 + dc*8;
    o0 += a * (*(const f32x4*)op);
    o1 += a * (*(const f32x4*)(op + 4));
  }
  float inv = 1.f / wsum;
  float* dst = out + (size_t)b*S_*64 + (size_t)(q0 + ql)*64 + dc*8;
  *(f32x4*)dst = o0 * inv;
  *(f32x4*)(dst + 4) = o1 * inv;
}

extern "C" void kernel_launch(void* const* d_in, const int* in_sizes, int n_in,
                              void* d_out, int out_size, void* d_ws, size_t ws_size,
                              hipStream_t stream)
{
  const float* x  = (const float*)d_in[0];
  const float* Wq = (const float*)d_in[1];
  const float* Wk = (const float*)d_in[2];
  const float* Wv = (const float*)d_in[3];
  unsigned short* Qp  = (unsigned short*)d_ws;                 // 2 MB
  unsigned short* Kbp = Qp  + (size_t)B_*S_*64;                // 2 MB
  unsigned short* Vtp = Kbp + (size_t)B_*S_*64;                // 2 MB
  float* out = (float*)d_out;

  const size_t qkv = (size_t)B_*S_*64*2*3;                     // 6,291,456 B
  // per split: Opart 4 MB + spart 128 KB
  const size_t per_ns = (size_t)512*2048*4 + (size_t)512*64*4; // 4,325,376 B
  int NS = (ws_size >= qkv + 4*per_ns) ? 4
         : (ws_size >= qkv + 2*per_ns) ? 2 : 1;
  float* Opart = (float*)((char*)d_ws + qkv);
  float* spart = (float*)((char*)d_ws + qkv + (size_t)NS*512*2048*4);

  hipLaunchKernelGGL(proj_kernel, dim3(256), dim3(256), 0, stream,
                     x, Wq, Wk, Wv, Qp, Kbp, Vtp);
  hipLaunchKernelGGL(attn_kernel, dim3(256*NS), dim3(256), 0, stream,
                     Qp, Kbp, Vtp, out, Opart, spart, NS);
  if (NS > 1)
    hipLaunchKernelGGL(merge_kernel, dim3(512), dim3(256), 0, stream,
                       Opart, spart, out, NS);
}

// Round 7
// 154.453 us; speedup vs baseline: 1.7277x; 1.0405x over previous
//
#include <hip/hip_runtime.h>
#include <hip/hip_bf16.h>
#include <math.h>

#define B_ 4
#define S_ 4096
#define E_ 1024

typedef __attribute__((ext_vector_type(8))) short bf16x8;
typedef __attribute__((ext_vector_type(4))) short bf16x4;
typedef __attribute__((ext_vector_type(4))) float f32x4;

__device__ __forceinline__ unsigned short f2bf(float f) {
  unsigned u = __float_as_uint(f);
  u = u + 0x7fffu + ((u >> 16) & 1u);
  return (unsigned short)(u >> 16);
}

// ---------------- projection: Q/K/Vt = x @ W^T ----------------
// (verbatim round-1 — proven correct)
__global__ __launch_bounds__(256) void proj_kernel(
    const float* __restrict__ x, const float* __restrict__ Wq,
    const float* __restrict__ Wk, const float* __restrict__ Wv,
    unsigned short* __restrict__ Qp, unsigned short* __restrict__ Kb,
    unsigned short* __restrict__ Vt)
{
  __shared__ __align__(16) unsigned short xs[64*64];   // [64 m][64 k] bf16, XOR-swizzled
  __shared__ __align__(16) unsigned short wl[192*64];  // [192 n][64 k] bf16, XOR-swizzled
  const int tid = threadIdx.x;
  const int wave = tid >> 6, lane = tid & 63;
  const int l15 = lane & 15, l4 = lane >> 4;
  const int m0 = blockIdx.x * 64;

  f32x4 acc[12];
  #pragma unroll
  for (int i = 0; i < 12; i++) acc[i] = (f32x4)0.f;

  f32x4 xr[4], wr[12];
  #pragma unroll
  for (int i = 0; i < 4; i++) {
    int c = tid + i*256; int row = c >> 4, cc = c & 15;
    xr[i] = *(const f32x4*)(x + (size_t)(m0 + row)*E_ + cc*4);
  }
  #pragma unroll
  for (int i = 0; i < 12; i++) {
    int c = tid + i*256; int n = c >> 4, cc = c & 15;
    const float* Wsrc = (n < 64) ? (Wq + (size_t)n*E_)
                     : ((n < 128) ? (Wk + (size_t)(n-64)*E_)
                                  : (Wv + (size_t)(n-128)*E_));
    wr[i] = *(const f32x4*)(Wsrc + cc*4);
  }

  for (int ks = 0; ks < 16; ks++) {
    __syncthreads();
    #pragma unroll
    for (int i = 0; i < 4; i++) {
      int c = tid + i*256; int row = c >> 4, cc = c & 15;
      bf16x4 v;
      v[0] = (short)f2bf(xr[i][0]); v[1] = (short)f2bf(xr[i][1]);
      v[2] = (short)f2bf(xr[i][2]); v[3] = (short)f2bf(xr[i][3]);
      *(bf16x4*)((char*)xs + row*128 + ((cc*8) ^ ((row&7)<<4))) = v;
    }
    #pragma unroll
    for (int i = 0; i < 12; i++) {
      int c = tid + i*256; int n = c >> 4, cc = c & 15;
      bf16x4 v;
      v[0] = (short)f2bf(wr[i][0]); v[1] = (short)f2bf(wr[i][1]);
      v[2] = (short)f2bf(wr[i][2]); v[3] = (short)f2bf(wr[i][3]);
      *(bf16x4*)((char*)wl + n*128 + ((cc*8) ^ ((n&7)<<4))) = v;
    }
    if (ks < 15) {
      #pragma unroll
      for (int i = 0; i < 4; i++) {
        int c = tid + i*256; int row = c >> 4, cc = c & 15;
        xr[i] = *(const f32x4*)(x + (size_t)(m0 + row)*E_ + (ks+1)*64 + cc*4);
      }
      #pragma unroll
      for (int i = 0; i < 12; i++) {
        int c = tid + i*256; int n = c >> 4, cc = c & 15;
        const float* Wsrc = (n < 64) ? (Wq + (size_t)n*E_)
                         : ((n < 128) ? (Wk + (size_t)(n-64)*E_)
                                      : (Wv + (size_t)(n-128)*E_));
        wr[i] = *(const f32x4*)(Wsrc + (ks+1)*64 + cc*4);
      }
    }
    __syncthreads();
    const int arow = wave*16 + l15;
    const int aswz = (arow&7)<<4;
    bf16x8 a0 = *(const bf16x8*)((const char*)xs + arow*128 + ((l4*16) ^ aswz));
    bf16x8 a1 = *(const bf16x8*)((const char*)xs + arow*128 + ((64 + l4*16) ^ aswz));
    #pragma unroll
    for (int ntl = 0; ntl < 12; ntl++) {
      int brow = ntl*16 + l15;
      int bswz = (brow&7)<<4;
      bf16x8 b0 = *(const bf16x8*)((const char*)wl + brow*128 + ((l4*16) ^ bswz));
      bf16x8 b1 = *(const bf16x8*)((const char*)wl + brow*128 + ((64 + l4*16) ^ bswz));
      acc[ntl] = __builtin_amdgcn_mfma_f32_16x16x32_bf16(a0, b0, acc[ntl], 0, 0, 0);
      acc[ntl] = __builtin_amdgcn_mfma_f32_16x16x32_bf16(a1, b1, acc[ntl], 0, 0, 0);
    }
  }

  const float QSC = 0.04508422f;  // log2(e) / sqrt(1024)
  const int mb = m0 + wave*16 + l4*4;
  #pragma unroll
  for (int ntl = 0; ntl < 4; ntl++) {
    int col = ntl*16 + l15;
    #pragma unroll
    for (int r = 0; r < 4; r++)
      Qp[(size_t)(mb + r)*64 + col] = f2bf(acc[ntl][r] * QSC);
  }
  #pragma unroll
  for (int ntl = 0; ntl < 4; ntl++) {
    int col = ntl*16 + l15;
    #pragma unroll
    for (int r = 0; r < 4; r++)
      Kb[(size_t)(mb + r)*64 + col] = f2bf(acc[4+ntl][r]);
  }
  const int b = m0 >> 12;
  const int sb = (m0 & 4095) + wave*16 + l4*4;
  #pragma unroll
  for (int ntl = 0; ntl < 4; ntl++) {
    int d = ntl*16 + l15;
    bf16x4 v;
    #pragma unroll
    for (int r = 0; r < 4; r++) v[r] = (short)f2bf(acc[8+ntl][r]);
    *(bf16x4*)(Vt + (size_t)(b*64 + d)*S_ + sb) = v;
  }
}

// ---------------- causal flash attention, QBLK=64 + split-K ----------------
// Block = (b, pair p, ks): 64-row q-blocks jq=p and jq=63-p, tile-slice ks.
// 4 waves; wave g owns q-rows g*16..g*16+15 and ALL 64 keys of each tile.
// Staging: 2 chunks/thread (512 chunks = full 64x64 bf16 tile) — R6's bug
// was staging only rows 0..31.
__global__ __launch_bounds__(256) void attn_kernel(
    const unsigned short* __restrict__ Qp,
    const unsigned short* __restrict__ Kb,
    const unsigned short* __restrict__ Vt,
    float* __restrict__ out,
    float* __restrict__ Opart, float* __restrict__ spart, int NS)
{
  __shared__ __align__(16) unsigned short Ks[64*64];  // [64 k][64 d], swizzled
  __shared__ __align__(16) unsigned short Vs[64*64];  // [64 d][64 k], swizzled

  const int tid = threadIdx.x;
  const int wave = tid >> 6, lane = tid & 63;
  const int l15 = lane & 15, l4 = lane >> 4;
  const int g = wave;                       // q-subgroup

  const int bid = blockIdx.x;               // grid = 4 * 32 * NS
  const int lg = (NS == 4) ? 2 : ((NS == 2) ? 1 : 0);
  const int b  = bid & 3;                   // batch spread across XCDs
  const int ks = (bid >> 2) & (NS - 1);
  const int p  = bid >> (2 + lg);           // 0..31

  const unsigned short* Qb  = Qp + (size_t)b*S_*64;
  const unsigned short* Kbb = Kb + (size_t)b*S_*64;
  const unsigned short* Vtb = Vt + (size_t)b*64*S_;
  float* outb = out + (size_t)b*S_*64;

  #pragma unroll 1
  for (int half = 0; half < 2; half++) {
    const int jq = half ? (63 - p) : p;          // 64-row q-block
    const int q0 = jq * 64;
    const int ntile = jq + 1;
    const int tb = ntile / NS, tr = ntile % NS;
    const int kbeg = ks*tb + (ks < tr ? ks : tr);
    const int kend = kbeg + tb + (ks < tr ? 1 : 0);
    const int qrow = q0 + g*16 + l15;

    bf16x8 qf0 = *(const bf16x8*)(Qb + (size_t)qrow*64 + l4*8);
    bf16x8 qf1 = *(const bf16x8*)(Qb + (size_t)qrow*64 + 32 + l4*8);

    float m = -INFINITY, lsum = 0.f;
    f32x4 acc[4];
    #pragma unroll
    for (int i = 0; i < 4; i++) acc[i] = (f32x4)0.f;

    f32x4 kreg[2], vreg[2];
    if (kbeg < kend) {
      #pragma unroll
      for (int i = 0; i < 2; i++) {
        int c = tid + i*256; int row = c >> 3, cc = c & 7;
        kreg[i] = *(const f32x4*)((const char*)Kbb + (size_t)(kbeg*64 + row)*128 + cc*16);
        vreg[i] = *(const f32x4*)((const char*)Vtb + (size_t)row*8192 + (size_t)kbeg*128 + cc*16);
      }
    }

    for (int t = kbeg; t < kend; t++) {
      __syncthreads();
      #pragma unroll
      for (int i = 0; i < 2; i++) {
        int c = tid + i*256; int row = c >> 3, cc = c & 7;
        *(f32x4*)((char*)Ks + row*128 + ((cc*16) ^ ((row&7)<<4))) = kreg[i];
        *(f32x4*)((char*)Vs + row*128 + ((cc*16) ^ ((row&7)<<4))) = vreg[i];
      }
      if (t + 1 < kend) {
        #pragma unroll
        for (int i = 0; i < 2; i++) {
          int c = tid + i*256; int row = c >> 3, cc = c & 7;
          kreg[i] = *(const f32x4*)((const char*)Kbb + (size_t)((t+1)*64 + row)*128 + cc*16);
          vreg[i] = *(const f32x4*)((const char*)Vtb + (size_t)row*8192 + (size_t)(t+1)*128 + cc*16);
        }
      }
      __syncthreads();

      // QK^T: this wave's 16 q-rows x all 64 keys (4 subtiles)
      f32x4 sv[4];
      #pragma unroll
      for (int kt = 0; kt < 4; kt++) {
        int krow = kt*16 + l15;
        const char* kbp = (const char*)Ks + krow*128;
        int swz = (krow&7)<<4;
        bf16x8 k0f = *(const bf16x8*)(kbp + ((l4*16) ^ swz));
        bf16x8 k1f = *(const bf16x8*)(kbp + ((64 + l4*16) ^ swz));
        f32x4 z = (f32x4)0.f;
        z = __builtin_amdgcn_mfma_f32_16x16x32_bf16(k0f, qf0, z, 0, 0, 0);
        z = __builtin_amdgcn_mfma_f32_16x16x32_bf16(k1f, qf1, z, 0, 0, 0);
        sv[kt] = z;
      }
      if (t == ntile - 1) {     // causal mask on diagonal tile
        #pragma unroll
        for (int kt = 0; kt < 4; kt++) {
          #pragma unroll
          for (int r = 0; r < 4; r++) {
            int kg = t*64 + kt*16 + l4*4 + r;
            if (kg > qrow) sv[kt][r] = -INFINITY;
          }
        }
      }
      // online softmax (base-2; Q pre-scaled by log2e/sqrt(E))
      float pmax = sv[0][0];
      #pragma unroll
      for (int kt = 0; kt < 4; kt++) {
        #pragma unroll
        for (int r = 0; r < 4; r++) pmax = fmaxf(pmax, sv[kt][r]);
      }
      pmax = fmaxf(pmax, __shfl_xor(pmax, 16, 64));
      pmax = fmaxf(pmax, __shfl_xor(pmax, 32, 64));
      float mnew = fmaxf(m, pmax);
      float msafe = (mnew == -INFINITY) ? 0.f : mnew;
      float scale = exp2f(m - msafe);
      float pv[16]; float psum = 0.f;
      #pragma unroll
      for (int i = 0; i < 16; i++) {
        pv[i] = exp2f(sv[i>>2][i&3] - msafe);
        psum += pv[i];
      }
      psum += __shfl_xor(psum, 16, 64);
      psum += __shfl_xor(psum, 32, 64);
      lsum = lsum*scale + psum;
      m = mnew;
      #pragma unroll
      for (int i = 0; i < 4; i++) acc[i] *= scale;
      bf16x8 pf0, pf1;
      #pragma unroll
      for (int i = 0; i < 8; i++) { pf0[i] = (short)f2bf(pv[i]); pf1[i] = (short)f2bf(pv[8+i]); }
      // O^T += V^T P^T over all 64 keys (two K=32 halves)
      #pragma unroll
      for (int dt = 0; dt < 4; dt++) {
        int drow = dt*16 + l15;
        const char* vb = (const char*)Vs + drow*128;
        int swz = (drow&7)<<4;
        bf16x4 a0 = *(const bf16x4*)(vb + ((l4*8) ^ swz));        // keys  0+l4*4
        bf16x4 a1 = *(const bf16x4*)(vb + ((32 + l4*8) ^ swz));   // keys 16+l4*4
        bf16x4 a2 = *(const bf16x4*)(vb + ((64 + l4*8) ^ swz));   // keys 32+l4*4
        bf16x4 a3 = *(const bf16x4*)(vb + ((96 + l4*8) ^ swz));   // keys 48+l4*4
        bf16x8 vf0, vf1;
        #pragma unroll
        for (int i = 0; i < 4; i++) {
          vf0[i] = a0[i]; vf0[i+4] = a1[i];
          vf1[i] = a2[i]; vf1[i+4] = a3[i];
        }
        acc[dt] = __builtin_amdgcn_mfma_f32_16x16x32_bf16(vf0, pf0, acc[dt], 0, 0, 0);
        acc[dt] = __builtin_amdgcn_mfma_f32_16x16x32_bf16(vf1, pf1, acc[dt], 0, 0, 0);
      }
    } // KV tiles

    // epilogue: wave writes its own 16 rows (no cross-wave merge needed)
    if (NS == 1) {
      float inv = 1.f / lsum;
      #pragma unroll
      for (int dt = 0; dt < 4; dt++)
        *(f32x4*)(outb + (size_t)qrow*64 + dt*16 + l4*4) = acc[dt] * inv;
    } else {
      int slot = (b*64 + jq)*NS + ks;
      float* Ob = Opart + (size_t)slot*4096 + (g*16 + l15)*64;
      #pragma unroll
      for (int dt = 0; dt < 4; dt++)
        *(f32x4*)(Ob + dt*16 + l4*4) = acc[dt];
      if (l4 == 0) {
        spart[(size_t)slot*128 + (g*16 + l15)*2]     = m;
        spart[(size_t)slot*128 + (g*16 + l15)*2 + 1] = lsum;
      }
    }
  } // half
}

// ---------------- cross-split merge ----------------
__global__ __launch_bounds__(256) void merge_kernel(
    const float* __restrict__ Opart, const float* __restrict__ spart,
    float* __restrict__ out, int NS)
{
  const int bid = blockIdx.x;          // 256 = 4 batches x 64 jq
  const int b = bid & 3, jq = bid >> 2;
  const int q = threadIdx.x >> 2;      // 0..63
  const int dq = threadIdx.x & 3;      // 16-float chunk
  const int base = (b*64 + jq) * NS;

  float M = -INFINITY;
  for (int i = 0; i < NS; i++)
    M = fmaxf(M, spart[(size_t)(base+i)*128 + q*2]);
  float wsum = 0.f;
  f32x4 o0 = (f32x4)0.f, o1 = (f32x4)0.f, o2 = (f32x4)0.f, o3 = (f32x4)0.f;
  for (int i = 0; i < NS; i++) {
    float mi = spart[(size_t)(base+i)*128 + q*2];
    float li = spart[(size_t)(base+i)*128 + q*2 + 1];
    float a = exp2f(mi - M);
    wsum += li * a;
    const float* op = Opart + (size_t)(base+i)*4096 + q*64 + dq*16;
    o0 += a * (*(const f32x4*)op);
    o1 += a * (*(const f32x4*)(op + 4));
    o2 += a * (*(const f32x4*)(op + 8));
    o3 += a * (*(const f32x4*)(op + 12));
  }
  float inv = 1.f / wsum;
  float* dst = out + (size_t)b*S_*64 + (size_t)(jq*64 + q)*64 + dq*16;
  *(f32x4*)dst       = o0 * inv;
  *(f32x4*)(dst + 4) = o1 * inv;
  *(f32x4*)(dst + 8) = o2 * inv;
  *(f32x4*)(dst + 12)= o3 * inv;
}

extern "C" void kernel_launch(void* const* d_in, const int* in_sizes, int n_in,
                              void* d_out, int out_size, void* d_ws, size_t ws_size,
                              hipStream_t stream)
{
  const float* x  = (const float*)d_in[0];
  const float* Wq = (const float*)d_in[1];
  const float* Wk = (const float*)d_in[2];
  const float* Wv = (const float*)d_in[3];
  unsigned short* Qp  = (unsigned short*)d_ws;                 // 2 MB
  unsigned short* Kbp = Qp  + (size_t)B_*S_*64;                // 2 MB
  unsigned short* Vtp = Kbp + (size_t)B_*S_*64;                // 2 MB
  float* out = (float*)d_out;

  const size_t qkv = (size_t)B_*S_*64*2*3;                     // 6,291,456 B
  // per split: Opart 256 slots x 16KB + spart 256 slots x 512B
  const size_t per_ns = (size_t)256*4096*4 + (size_t)256*128*4;
  int NS = (ws_size >= qkv + 4*per_ns) ? 4
         : (ws_size >= qkv + 2*per_ns) ? 2 : 1;
  float* Opart = (float*)((char*)d_ws + qkv);
  float* spart = (float*)((char*)d_ws + qkv + (size_t)NS*256*4096*4);

  hipLaunchKernelGGL(proj_kernel, dim3(256), dim3(256), 0, stream,
                     x, Wq, Wk, Wv, Qp, Kbp, Vtp);
  hipLaunchKernelGGL(attn_kernel, dim3(4*32*NS), dim3(256), 0, stream,
                     Qp, Kbp, Vtp, out, Opart, spart, NS);
  if (NS > 1)
    hipLaunchKernelGGL(merge_kernel, dim3(256), dim3(256), 0, stream,
                       Opart, spart, out, NS);
}